// Round 9
// baseline (81.422 us; speedup 1.0000x reference)
//
#include <hip/hip_runtime.h>
#include <math.h>

#define N 8
#define C 128
#define L 1024
#define K 100
#define TEMP 0.5f
#define EPS 1e-8f
#define NT (N * L)

#define D  8    // row-pipeline depth (iters of 4 rows each in flight)
#define IB 10   // index-pipeline depth (>= D+2)

typedef _Float16 h2 __attribute__((ext_vector_type(2)));
typedef _Float16 v8h __attribute__((ext_vector_type(8)));

__device__ __forceinline__ float fd2(h2 a, h2 b, float acc) {
#if __has_builtin(__builtin_amdgcn_fdot2)
    return __builtin_amdgcn_fdot2(a, b, acc, false);
#else
    return acc + (float)a[0] * (float)b[0] + (float)a[1] * (float)b[1];
#endif
}

// sum over 16-lane row via DPP row_ror chain (no LDS pipe traffic)
#if __has_builtin(__builtin_amdgcn_mov_dpp)
#define ROR_ADD(x, r) ((x) + __int_as_float(__builtin_amdgcn_mov_dpp(__float_as_int(x), 0x120 + (r), 0xF, 0xF, true)))
#else
#define ROR_ADD(x, r) ((x) + __shfl_xor((x), (r)))   // xor-chain fallback: same sum
#endif

// Fused transpose + full-row-norm + normalize + fp16 store (from R8, verified).
//   z'[n][l][ch] = z/max(||z_l||,EPS);  c'[n][l][ch] = 2*c/max(||c_l||,EPS)
// so logit = dot(c', z') exactly matches dot/(cn*tn)/TEMP.
__global__ void __launch_bounds__(256)
norm_transpose(const float* __restrict__ z, const float* __restrict__ c,
               _Float16* __restrict__ z_h, _Float16* __restrict__ c_h) {
    __shared__ float tile[C][33];
    __shared__ float part[8][32];
    __shared__ float scale_s[32];
    const int chunk = blockIdx.x;
    const int which = blockIdx.y;
    const int n = blockIdx.z;
    const float* src = which ? c : z;
    _Float16* dst = which ? c_h : z_h;
    const int slen = which ? (L + 1) : L;
    const int off = which;
    const int tid = threadIdx.x;
    const int tx = tid & 31;
    const int ty = tid >> 5;

#pragma unroll
    for (int i = 0; i < 16; i++) {
        int ch = ty + 8 * i;
        tile[ch][tx] = src[((size_t)(n * C + ch)) * slen + off + chunk * 32 + tx];
    }
    __syncthreads();
    float sm = 0.f;
#pragma unroll
    for (int i = 0; i < 16; i++) { float v = tile[ty * 16 + i][tx]; sm += v * v; }
    part[ty][tx] = sm;
    __syncthreads();
    if (ty == 0) {
        float s2 = 0.f;
#pragma unroll
        for (int i = 0; i < 8; i++) s2 += part[i][tx];
        float nrm = fmaxf(sqrtf(s2), EPS);
        scale_s[tx] = (which ? 2.0f : 1.0f) / nrm;
    }
    __syncthreads();
    const int ch = tid & 127;
    const int lq = tid >> 7;
#pragma unroll
    for (int j = 0; j < 16; j++) {
        int l = lq + 2 * j;
        dst[((size_t)(n * L + chunk * 32 + l)) * C + ch] =
            (_Float16)(tile[ch][l] * scale_s[l]);
    }
}

// One wave per (n,t). 16 lanes per target (lane s holds 16B chunk s), 4 targets
// per iter, 26 iters. One global_load_dwordx4 = 4 complete rows (1 KB).
// 8-deep row pipeline (32 VGPRs), 10-deep index pipeline. DPP row_ror reduce.
__global__ void __launch_bounds__(256)
ssl3(const _Float16* __restrict__ zh, const _Float16* __restrict__ chh,
     const int* __restrict__ neg,
     const float* __restrict__ z_orig, const float* __restrict__ c_orig,
     float* __restrict__ out) {
    const int tid  = threadIdx.x;
    const int lane = tid & 63;
    const int g    = lane >> 4;          // target group 0..3
    const int s    = lane & 15;          // 16B chunk within row
    const int nt   = blockIdx.x * 4 + (tid >> 6);
    const int n    = nt >> 10;
    const int t    = nt & (L - 1);

    const v8h cf = ((const v8h*)(chh + (size_t)nt * C))[s];
    const int* ni = neg + (size_t)nt * K;
    const _Float16* zbase = zh + (((size_t)n) << 10) * C;
    float* orow = out + (size_t)nt * (K + 1);

    int idxb[IB];
    v8h rowb[D];
#pragma unroll
    for (int j = 0; j < IB; j++) {
        int kk = j * 4 + g;
        idxb[j] = (kk == 0) ? t : ((kk <= K) ? ni[kk - 1] : 0);
    }
#pragma unroll
    for (int j = 0; j < D; j++)
        rowb[j] = ((const v8h*)(zbase + (size_t)idxb[j] * C))[s];

#pragma unroll
    for (int i = 0; i < 26; i++) {
        const v8h zv    = rowb[i % D];
        const int idx_i = idxb[i % IB];

        if (i + IB < 26) {                       // refill index slot (iter i+IB)
            int kk2 = (i + IB) * 4 + g;
            idxb[(i + IB) % IB] = (kk2 <= K) ? ni[kk2 - 1] : 0;
        }
        if (i + D < 26)                          // issue rows for iter i+D
            rowb[(i + D) % D] =
                ((const v8h*)(zbase + (size_t)idxb[(i + D) % IB] * C))[s];

        const h2* cz = (const h2*)&cf;
        const h2* zz = (const h2*)&zv;
        float d0 = 0.f, d1 = 0.f;
        d0 = fd2(cz[0], zz[0], d0);
        d1 = fd2(cz[1], zz[1], d1);
        d0 = fd2(cz[2], zz[2], d0);
        d1 = fd2(cz[3], zz[3], d1);
        float dot = d0 + d1;
        dot = ROR_ADD(dot, 1);
        dot = ROR_ADD(dot, 2);
        dot = ROR_ADD(dot, 4);
        dot = ROR_ADD(dot, 8);                   // all 16 lanes hold the sum

        int kk = i * 4 + g;
        if (s == 0 && kk <= K) {
            float logit = dot;                   // pre-normalized: dot IS the logit
            if (kk > 0 && dot > 1.9f) {
                // only bit-equal rows land here (dot~2.0 vs <=~0.9 random): exact recheck
                bool eq = true;
                for (int q = 0; q < C; q++)
                    eq = eq && (c_orig[((size_t)(n * C + q)) * (L + 1) + t + 1] ==
                                z_orig[((size_t)(n * C + q)) * L + idx_i]);
                if (eq) logit = -INFINITY;
            }
            orow[kk] = logit;
        }
    }
}

extern "C" void kernel_launch(void* const* d_in, const int* in_sizes, int n_in,
                              void* d_out, int out_size, void* d_ws, size_t ws_size,
                              hipStream_t stream) {
    const float* z   = (const float*)d_in[0];   // (N, C, L)
    const float* c   = (const float*)d_in[1];   // (N, C, L+1)
    const int*   neg = (const int*)d_in[2];     // (N, L, K)
    float* out = (float*)d_out;                 // (N*L, K+1)

    _Float16* z_h = (_Float16*)d_ws;            // (N, L, C) normalized fp16, 2 MB
    _Float16* c_h = z_h + (size_t)NT * C;       // (N, L, C) normalized fp16 (x2 folded)

    norm_transpose<<<dim3(32, 2, N), 256, 0, stream>>>(z, c, z_h, c_h);
    ssl3<<<dim3(NT / 4), 256, 0, stream>>>(z_h, c_h, neg, z, c, out);
}